// Round 4
// baseline (6251.643 us; speedup 1.0000x reference)
//
#include <hip/hip_runtime.h>

// ---------------------------------------------------------------------------
// AdderNet 6-layer stack on MI355X (gfx950).
// out[n,o,p] = -sum_k |patch[p,k] - w[o,k]|   (VALU-bound; no MFMA possible)
// BN(batch stats)+ReLU6 of layer i folded into layer i+1's staging load.
//
// R4: register-prefetch pipeline + double-buffered LDS (1 barrier/chunk,
// global latency hidden under compute), launch_bounds(256,3) so the
// compiler isn't register-starved (R3: VGPR=44 with 32 live accs => bloat),
// 52KB LDS => exactly 3 blocks/CU resident.
// ---------------------------------------------------------------------------

template <bool IS3x3, bool BN>
__global__ __launch_bounds__(256, 3)
void adder_conv(const float* __restrict__ x, const float* __restrict__ wT,
                const float2* __restrict__ ab, float* __restrict__ part,
                int Cin, int H, int W, int Wo, int Cout,
                int stride, int pad, int cpz, int P, int PI, int Pp)
{
    constexpr int KC = 32;
    __shared__ float xs[2][KC][64];    // 16 KB
    __shared__ float ws[2][KC][128];   // 32 KB
    __shared__ float2 abls[512];       //  4 KB  -> 52 KB total, 3 blocks/CU

    const int t  = threadIdx.x;
    const int tx = t & 15, ty = t >> 4;          // compute: 4 pix x 8 och
    const int ptile = blockIdx.x * 64, otile = blockIdx.y * 128;
    const int pp = t & 63, rg = t >> 6;          // xs staging: pixel, k-group
    const int oq = t & 31, kr = t >> 5;          // ws staging: och-quad, k-row

    if (BN) {
        for (int i = t; i < Cin; i += 256) abls[i] = ab[i];
    }

    // staging pixel decode (fixed per thread)
    const int p_st = ptile + pp;
    const bool pv = p_st < P;
    int n_st = 0, q = 0;
    if (pv) { n_st = p_st / PI; q = p_st - n_st * PI; }
    const int oh = q / Wo, ow = q - oh * Wo;
    const int ih0 = oh * stride - pad, iw0 = ow * stride - pad;
    const int HWi = H * W;
    const float* xb = x + (size_t)n_st * Cin * HWi;

    const int chunkBeg = blockIdx.z * cpz, chunkEnd = chunkBeg + cpz;

    float  xr[8];
    float4 wr[4];
    int    cbase = 0;
    bool   vld = false;

    auto loadChunk = [&](int ch) {
        const int k0 = ch * KC;
        int c0, ih, iw;
        if (IS3x3) {
            const int tap = k0 / Cin;            // uniform per chunk (Cin%32==0)
            c0 = k0 - tap * Cin;
            const int kh = tap / 3, kw = tap - kh * 3;
            ih = ih0 + kh; iw = iw0 + kw;
        } else { c0 = k0; ih = ih0; iw = iw0; }
        cbase = c0;
        vld = pv && (!IS3x3 || ((unsigned)ih < (unsigned)H && (unsigned)iw < (unsigned)W));
        const float* px = xb + (size_t)(c0 + rg) * HWi + (ih * W + iw);
#pragma unroll
        for (int j = 0; j < 8; ++j)
            xr[j] = vld ? px[(size_t)(4 * j) * HWi] : 0.f;
        const float* pw = wT + (size_t)(k0 + kr) * Cout + otile + oq * 4;
#pragma unroll
        for (int j = 0; j < 4; ++j)
            wr[j] = *(const float4*)(pw + (size_t)(8 * j) * Cout);
    };

    auto writeChunk = [&](int buf) {
#pragma unroll
        for (int j = 0; j < 8; ++j) {
            float v = xr[j];
            if (BN) {
                const float2 s = abls[cbase + rg + 4 * j];
                v = vld ? fminf(fmaxf(fmaf(s.x, v, s.y), 0.f), 6.f) : 0.f;
            }
            xs[buf][rg + 4 * j][pp] = v;
        }
#pragma unroll
        for (int j = 0; j < 4; ++j)
            *(float4*)&ws[buf][kr + 8 * j][oq * 4] = wr[j];
    };

    float acc[4][8] = {};

    auto compute = [&](int buf) {
        const float(*__restrict__ xsb)[64]  = xs[buf];
        const float(*__restrict__ wsb)[128] = ws[buf];
#pragma unroll
        for (int kk = 0; kk < KC; ++kk) {
            const float4 xv = *(const float4*)&xsb[kk][tx * 4];
            const float4 wa = *(const float4*)&wsb[kk][ty * 8];
            const float4 wb = *(const float4*)&wsb[kk][ty * 8 + 4];
#define ACC1(I, XC)                                             \
            acc[I][0] += __builtin_fabsf(XC - wa.x);            \
            acc[I][1] += __builtin_fabsf(XC - wa.y);            \
            acc[I][2] += __builtin_fabsf(XC - wa.z);            \
            acc[I][3] += __builtin_fabsf(XC - wa.w);            \
            acc[I][4] += __builtin_fabsf(XC - wb.x);            \
            acc[I][5] += __builtin_fabsf(XC - wb.y);            \
            acc[I][6] += __builtin_fabsf(XC - wb.z);            \
            acc[I][7] += __builtin_fabsf(XC - wb.w);
            ACC1(0, xv.x) ACC1(1, xv.y) ACC1(2, xv.z) ACC1(3, xv.w)
#undef ACC1
        }
    };

    // ---- pipeline: load ch+1 into regs while computing ch from LDS
    loadChunk(chunkBeg);
    __syncthreads();                 // abls visible before writeChunk reads it
    writeChunk(0);
    __syncthreads();
    int cur = 0;
    for (int ch = chunkBeg + 1; ch < chunkEnd; ++ch) {
        loadChunk(ch);
        compute(cur);
        writeChunk(cur ^ 1);
        __syncthreads();
        cur ^= 1;
    }
    compute(cur);

    // ---- plain coalesced stores into this z-slice's partial buffer
    const int p0 = ptile + tx * 4;
    const bool full = (p0 + 3) < P;
#pragma unroll
    for (int jj = 0; jj < 8; ++jj) {
        const int o = otile + ty * 8 + jj;
        float* dst = part + ((size_t)blockIdx.z * Cout + o) * Pp + p0;
        if (full) {
            *(float4*)dst = make_float4(acc[0][jj], acc[1][jj], acc[2][jj], acc[3][jj]);
        } else {
#pragma unroll
            for (int i = 0; i < 4; ++i)
                if (p0 + i < P) dst[i] = acc[i][jj];
        }
    }
}

// fused: sum Z partial slices, negate -> final layout [n][c][PI], and
// accumulate per-channel sum/sumsq (double) for BN stats.
__global__ void combine_stats(const float* __restrict__ part, float* __restrict__ fin,
                              double* __restrict__ st, int C, int PI, int Z, int Pp)
{
    const int c = blockIdx.x, n = blockIdx.y, t = threadIdx.x;
    const int pbase = n * PI;
    double s = 0.0, s2 = 0.0;
    for (int qq = t; qq < PI; qq += 256) {
        float v = 0.f;
        for (int z = 0; z < Z; ++z)
            v += part[((size_t)z * C + c) * Pp + pbase + qq];
        v = -v;
        fin[((size_t)n * C + c) * PI + qq] = v;
        s += v; s2 += (double)v * v;
    }
    __shared__ double sh[256], sh2[256];
    sh[t] = s; sh2[t] = s2; __syncthreads();
    for (int off = 128; off > 0; off >>= 1) {
        if (t < off) { sh[t] += sh[t + off]; sh2[t] += sh2[t + off]; }
        __syncthreads();
    }
    if (t == 0) {
        unsafeAtomicAdd(&st[2 * c], sh[0]);
        unsafeAtomicAdd(&st[2 * c + 1], sh2[0]);
    }
}

// per-channel affine fold: a = g*rsqrt(var+eps), b = beta - mean*a
__global__ void ab_kernel(const double* __restrict__ st, const float* __restrict__ gamma,
                          const float* __restrict__ beta, float2* __restrict__ ab,
                          int C, double invCount)
{
    const int c = blockIdx.x * blockDim.x + threadIdx.x;
    if (c < C) {
        const double mean = st[2 * c] * invCount;
        const double var  = st[2 * c + 1] * invCount - mean * mean;
        const float a = gamma[c] * rsqrtf((float)var + 1e-5f);
        const float b = beta[c] - (float)mean * a;
        ab[c] = make_float2(a, b);
    }
}

// final BN+ReLU6 -> d_out
__global__ void apply_kernel(const float* __restrict__ y, const float2* __restrict__ ab,
                             float* __restrict__ out, int total, int C, int PI)
{
    const int i = blockIdx.x * 256 + threadIdx.x;
    if (i < total) {
        const int c = (i / PI) % C;
        const float2 s = ab[c];
        out[i] = fminf(fmaxf(fmaf(s.x, y[i], s.y), 0.f), 6.f);
    }
}

// merged weight transposes: w [Cout][Cin][tap] -> wT [tap*Cin + c][Cout]
struct TDesc { const float* w; float* wT; int Cout; int Cin; int Tap; int elems; };
struct TPack { TDesc d[6]; };

__global__ void transpose_all(TPack p)
{
    const TDesc d = p.d[blockIdx.y];
    const int i = blockIdx.x * 256 + threadIdx.x;
    if (i < d.elems) {
        const int k = i / d.Cout, o = i - k * d.Cout;
        const int tap = k / d.Cin, c = k - tap * d.Cin;
        d.wT[i] = d.w[((size_t)o * d.Cin + c) * d.Tap + tap];
    }
}

extern "C" void kernel_launch(void* const* d_in, const int* in_sizes, int n_in,
                              void* d_out, int out_size, void* d_ws, size_t ws_size,
                              hipStream_t stream)
{
    const float* x = (const float*)d_in[0];
    const float *w[6], *g[6], *bt[6];
    for (int i = 0; i < 6; ++i) {
        w[i]  = (const float*)d_in[1 + 3 * i];
        g[i]  = (const float*)d_in[2 + 3 * i];
        bt[i] = (const float*)d_in[3 + 3 * i];
    }

    char* ws = (char*)d_ws;
    float* bufA = (float*)ws;                                   // 23,658,496 B
    float* bufB = (float*)(ws + 23658496);                      // 11,829,248 B
    float* part = (float*)(ws + 23658496 + 11829248);           // 23,658,496 B
    size_t off = 23658496 + 11829248 + 23658496;
    const int wElems[6] = {256 * 512, 512 * 2304, 128 * 512,
                           256 * 1152, 128 * 256, 256 * 1152};
    float* wT[6];
    for (int i = 0; i < 6; ++i) { wT[i] = (float*)(ws + off); off += (size_t)wElems[i] * 4; }
    double* st = (double*)(ws + off); off += 3072 * 8;
    float2* ab = (float2*)(ws + off);
    const int stOff[6] = {0, 512, 1536, 1792, 2304, 2560};
    const int abOff[6] = {0, 256, 768, 896, 1152, 1280};

    const dim3 blk(256);

    // zero stats accumulators (ws is poisoned 0xAA before every launch)
    hipMemsetAsync(st, 0, 3072 * 8, stream);

    // merged weight transposes (tap-major k order)
    TPack tp;
    const int wCout[6] = {256, 512, 128, 256, 128, 256};
    const int wCin[6]  = {512, 256, 512, 128, 256, 128};
    const int wTap[6]  = {1, 9, 1, 9, 1, 9};
    for (int i = 0; i < 6; ++i)
        tp.d[i] = TDesc{w[i], wT[i], wCout[i], wCin[i], wTap[i], wElems[i]};
    transpose_all<<<dim3((1179648 + 255) / 256, 6), blk, 0, stream>>>(tp);

    // ---- L1: 1x1, 512->256, 38x38, P=23104, K=512, Z=1 (722 blocks)
    adder_conv<false, false><<<dim3(361, 2, 1), blk, 0, stream>>>(
        x, wT[0], nullptr, part, 512, 38, 38, 38, 256, 1, 0, 16, 23104, 1444, 23104);
    combine_stats<<<dim3(256, 16), blk, 0, stream>>>(part, bufA, st + stOff[0], 256, 1444, 1, 23104);
    ab_kernel<<<1, blk, 0, stream>>>(st + stOff[0], g[0], bt[0], ab + abOff[0], 256, 1.0 / 23104);

    // ---- L2: 3x3 s2 p1, 256->512, 38->19, P=5776, K=2304, Z=2 (728 blocks)
    adder_conv<true, true><<<dim3(91, 4, 2), blk, 0, stream>>>(
        bufA, wT[1], ab + abOff[0], part, 256, 38, 38, 19, 512, 2, 1, 36, 5776, 361, 5776);
    combine_stats<<<dim3(512, 16), blk, 0, stream>>>(part, bufB, st + stOff[1], 512, 361, 2, 5776);
    ab_kernel<<<2, blk, 0, stream>>>(st + stOff[1], g[1], bt[1], ab + abOff[1], 512, 1.0 / 5776);

    // ---- L3: 1x1, 512->128, 19x19, P=5776, K=512, Z=8 (728 blocks)
    adder_conv<false, true><<<dim3(91, 1, 8), blk, 0, stream>>>(
        bufB, wT[2], ab + abOff[1], part, 512, 19, 19, 19, 128, 1, 0, 2, 5776, 361, 5776);
    combine_stats<<<dim3(128, 16), blk, 0, stream>>>(part, bufA, st + stOff[2], 128, 361, 8, 5776);
    ab_kernel<<<1, blk, 0, stream>>>(st + stOff[2], g[2], bt[2], ab + abOff[2], 128, 1.0 / 5776);

    // ---- L4: 3x3 s2 p1, 128->256, 19->10, P=1600, K=1152, Z=6 (300 blocks)
    adder_conv<true, true><<<dim3(25, 2, 6), blk, 0, stream>>>(
        bufA, wT[3], ab + abOff[2], part, 128, 19, 19, 10, 256, 2, 1, 6, 1600, 100, 1600);
    combine_stats<<<dim3(256, 16), blk, 0, stream>>>(part, bufB, st + stOff[3], 256, 100, 6, 1600);
    ab_kernel<<<1, blk, 0, stream>>>(st + stOff[3], g[3], bt[3], ab + abOff[3], 256, 1.0 / 1600);

    // ---- L5: 1x1, 256->128, 10x10, P=1600, K=256, Z=8 (200 blocks)
    adder_conv<false, true><<<dim3(25, 1, 8), blk, 0, stream>>>(
        bufB, wT[4], ab + abOff[3], part, 256, 10, 10, 10, 128, 1, 0, 1, 1600, 100, 1600);
    combine_stats<<<dim3(128, 16), blk, 0, stream>>>(part, bufA, st + stOff[4], 128, 100, 8, 1600);
    ab_kernel<<<1, blk, 0, stream>>>(st + stOff[4], g[4], bt[4], ab + abOff[4], 128, 1.0 / 1600);

    // ---- L6: 3x3 s2 p0, 128->256, 10->4, P=256, K=1152, Z=18 (144 blocks)
    adder_conv<true, true><<<dim3(4, 2, 18), blk, 0, stream>>>(
        bufA, wT[5], ab + abOff[4], part, 128, 10, 10, 4, 256, 2, 0, 2, 256, 16, 256);
    combine_stats<<<dim3(256, 16), blk, 0, stream>>>(part, bufB, st + stOff[5], 256, 16, 18, 256);
    ab_kernel<<<1, blk, 0, stream>>>(st + stOff[5], g[5], bt[5], ab + abOff[5], 256, 1.0 / 256);

    // ---- final BN+ReLU6 -> out
    apply_kernel<<<(65536 + 255) / 256, blk, 0, stream>>>(bufB, ab + abOff[5], (float*)d_out,
                                                          65536, 256, 16);
}

// Round 5
// 1415.581 us; speedup vs baseline: 4.4163x; 4.4163x over previous
//
#include <hip/hip_runtime.h>

// ---------------------------------------------------------------------------
// AdderNet 6-layer stack on MI355X (gfx950).
// out[n,o,p] = -sum_k |x[p,k] - w[o,k]|   (VALU-bound; no MFMA possible)
//
// R5: LDS-free conv. lane = pixel, weights are wave-uniform -> SGPRs via
// s_load (scalar pipe), activations cached in xreg[32] VGPRs and reused
// across OB output channels. Inner loop = v_sub + v_add(|mod|) per MAC,
// no LDS, no barriers, no split-K. BN stats reduced in-register via
// __shfl_xor + one f64 atomic per wave per channel. BN+ReLU6 materialized
// by an elementwise prep pass between layers.
// R4 lesson: no capture-by-ref private arrays (scratch spill, 14GB/dispatch).
// ---------------------------------------------------------------------------

template <int OB, bool IS3x3>
__global__ __launch_bounds__(256)
void adder_conv(const float* __restrict__ x, const float* __restrict__ wP,
                float* __restrict__ y, double* __restrict__ st,
                int Cin, int H, int W, int Wo, int stride, int pad,
                int K, int Cout, int chunks, int P, int PI)
{
    const int t    = threadIdx.x;
    const int lane = t & 63;
    const int wid  = __builtin_amdgcn_readfirstlane(t >> 6);   // uniform wave id
    const int otile = (blockIdx.x * 4 + wid) * OB;             // uniform
    const int p    = blockIdx.y * 64 + lane;
    const bool pvalid = p < P;

    // per-lane pixel decode (once)
    int n = 0, q = 0;
    if (pvalid) { n = p / PI; q = p - n * PI; }
    const int oh = q / Wo, ow = q - oh * Wo;
    const int ih0 = oh * stride - pad, iw0 = ow * stride - pad;
    const int HWi = H * W;
    const float* xb = x + (size_t)n * Cin * HWi;

    float acc[OB];
#pragma unroll
    for (int i = 0; i < OB; ++i) acc[i] = 0.f;

    for (int ch = 0; ch < chunks; ++ch) {
        const int k0 = ch * 32;                 // uniform
        int c0, ih, iw;
        if (IS3x3) {
            const int tap = k0 / Cin;           // uniform (Cin % 32 == 0)
            c0 = k0 - tap * Cin;
            const int kh = tap / 3, kw = tap - kh * 3;
            ih = ih0 + kh; iw = iw0 + kw;
        } else { c0 = k0; ih = ih0; iw = iw0; }
        const bool vld = pvalid &&
            (!IS3x3 || ((unsigned)ih < (unsigned)H && (unsigned)iw < (unsigned)W));
        const float* px = xb + (size_t)c0 * HWi + (ih * W + iw);

        // ---- x chunk into registers (lane = pixel; OOB/padding -> 0)
        float xreg[32];
#pragma unroll
        for (int kk = 0; kk < 32; ++kk) xreg[kk] = 0.f;
        if (vld) {
#pragma unroll
            for (int kk = 0; kk < 32; ++kk) xreg[kk] = px[(size_t)kk * HWi];
        }

        // ---- och pairs: weights uniform -> s_load; 2 indep acc chains
#pragma unroll
        for (int ob = 0; ob < OB; ob += 2) {
            const float* w0 = wP + (size_t)(otile + ob)     * K + k0;
            const float* w1 = wP + (size_t)(otile + ob + 1) * K + k0;
            float a0 = acc[ob], a1 = acc[ob + 1];
#pragma unroll
            for (int kk = 0; kk < 32; ++kk) {
                a0 += __builtin_fabsf(xreg[kk] - w0[kk]);
                a1 += __builtin_fabsf(xreg[kk] - w1[kk]);
            }
            acc[ob] = a0; acc[ob + 1] = a1;
        }
    }

    // ---- epilogue: negate, store final y, in-register BN stats
#pragma unroll
    for (int ob = 0; ob < OB; ++ob) {
        const int o = otile + ob;
        const float v = pvalid ? -acc[ob] : 0.f;
        if (pvalid) y[((size_t)n * Cout + o) * PI + q] = v;
        float s = v, s2 = v * v;
#pragma unroll
        for (int m = 32; m > 0; m >>= 1) {
            s  += __shfl_xor(s,  m);
            s2 += __shfl_xor(s2, m);
        }
        if (lane == 0) {
            unsafeAtomicAdd(&st[2 * o],     (double)s);
            unsafeAtomicAdd(&st[2 * o + 1], (double)s2);
        }
    }
}

// per-channel affine fold: a = g*rsqrt(var+eps), b = beta - mean*a
__global__ void ab_kernel(const double* __restrict__ st, const float* __restrict__ gamma,
                          const float* __restrict__ beta, float2* __restrict__ ab,
                          int C, double invCount)
{
    const int c = blockIdx.x * blockDim.x + threadIdx.x;
    if (c < C) {
        const double mean = st[2 * c] * invCount;
        const double var  = st[2 * c + 1] * invCount - mean * mean;
        const float a = gamma[c] * rsqrtf((float)var + 1e-5f);
        const float b = beta[c] - (float)mean * a;
        ab[c] = make_float2(a, b);
    }
}

// BN+ReLU6 materialize: dst[n,c,:] = clamp(a*y+b, 0, 6). blockIdx.y = n*C + c.
__global__ void prep_kernel(const float* __restrict__ y, const float2* __restrict__ ab,
                            float* __restrict__ dst, int C, int PI)
{
    const int c = blockIdx.y % C;
    const int i = blockIdx.x * 256 + threadIdx.x;
    if (i < PI) {
        const size_t base = (size_t)blockIdx.y * PI;
        const float2 s = ab[c];
        dst[base + i] = fminf(fmaxf(fmaf(s.x, y[base + i], s.y), 0.f), 6.f);
    }
}

// merged weight transposes: w [o][c][tap] -> wP [o][tap][c]  (k = tap*Cin+c)
struct TDesc { const float* w; float* wP; int Cin; int Tap; int K; int elems; };
struct TPack { TDesc d[6]; };

__global__ void transpose_all(TPack p)
{
    const TDesc d = p.d[blockIdx.y];
    const int i = blockIdx.x * 256 + threadIdx.x;
    if (i < d.elems) {
        const int o = i / d.K, r = i - o * d.K;
        const int tap = r / d.Cin, c = r - tap * d.Cin;
        d.wP[i] = d.w[((size_t)o * d.Cin + c) * d.Tap + tap];
    }
}

extern "C" void kernel_launch(void* const* d_in, const int* in_sizes, int n_in,
                              void* d_out, int out_size, void* d_ws, size_t ws_size,
                              hipStream_t stream)
{
    const float* x = (const float*)d_in[0];
    const float *w[6], *g[6], *bt[6];
    for (int i = 0; i < 6; ++i) {
        w[i]  = (const float*)d_in[1 + 3 * i];
        g[i]  = (const float*)d_in[2 + 3 * i];
        bt[i] = (const float*)d_in[3 + 3 * i];
    }

    char* ws = (char*)d_ws;
    float* bufY = (float*)ws;                                   // 23,658,496 B
    float* bufX = (float*)(ws + 23658496);                      // 23,658,496 B
    size_t off = 2ull * 23658496;
    const int wElems[6] = {256 * 512, 512 * 2304, 128 * 512,
                           256 * 1152, 128 * 256, 256 * 1152};
    float* wP[6];
    for (int i = 0; i < 6; ++i) { wP[i] = (float*)(ws + off); off += (size_t)wElems[i] * 4; }
    double* st = (double*)(ws + off); off += 3072 * 8;
    float2* ab = (float2*)(ws + off);
    const int stOff[6] = {0, 512, 1536, 1792, 2304, 2560};
    const int abOff[6] = {0, 256, 768, 896, 1152, 1280};

    const dim3 blk(256);

    // zero stats accumulators (ws is poisoned 0xAA before every launch)
    hipMemsetAsync(st, 0, 3072 * 8, stream);

    // merged weight transposes (k = tap-major)
    TPack tp;
    const int wCin[6] = {512, 256, 512, 128, 256, 128};
    const int wTap[6] = {1, 9, 1, 9, 1, 9};
    for (int i = 0; i < 6; ++i)
        tp.d[i] = TDesc{w[i], wP[i], wCin[i], wTap[i], wCin[i] * wTap[i], wElems[i]};
    transpose_all<<<dim3((1179648 + 255) / 256, 6), blk, 0, stream>>>(tp);

    // ---- L1: 1x1, 512->256, 38x38, P=23104, PI=1444, K=512, OB=32
    adder_conv<32, false><<<dim3(2, 361), blk, 0, stream>>>(
        x, wP[0], bufY, st + stOff[0], 512, 38, 38, 38, 1, 0, 512, 256, 16, 23104, 1444);
    ab_kernel<<<1, blk, 0, stream>>>(st + stOff[0], g[0], bt[0], ab + abOff[0], 256, 1.0 / 23104);
    prep_kernel<<<dim3(6, 16 * 256), blk, 0, stream>>>(bufY, ab + abOff[0], bufX, 256, 1444);

    // ---- L2: 3x3 s2 p1, 256->512, 38->19, P=5776, PI=361, K=2304, OB=16
    adder_conv<16, true><<<dim3(8, 91), blk, 0, stream>>>(
        bufX, wP[1], bufY, st + stOff[1], 256, 38, 38, 19, 2, 1, 2304, 512, 72, 5776, 361);
    ab_kernel<<<2, blk, 0, stream>>>(st + stOff[1], g[1], bt[1], ab + abOff[1], 512, 1.0 / 5776);
    prep_kernel<<<dim3(2, 16 * 512), blk, 0, stream>>>(bufY, ab + abOff[1], bufX, 512, 361);

    // ---- L3: 1x1, 512->128, 19x19, P=5776, PI=361, K=512, OB=8
    adder_conv<8, false><<<dim3(4, 91), blk, 0, stream>>>(
        bufX, wP[2], bufY, st + stOff[2], 512, 19, 19, 19, 1, 0, 512, 128, 16, 5776, 361);
    ab_kernel<<<1, blk, 0, stream>>>(st + stOff[2], g[2], bt[2], ab + abOff[2], 128, 1.0 / 5776);
    prep_kernel<<<dim3(2, 16 * 128), blk, 0, stream>>>(bufY, ab + abOff[2], bufX, 128, 361);

    // ---- L4: 3x3 s2 p1, 128->256, 19->10, P=1600, PI=100, K=1152, OB=8
    adder_conv<8, true><<<dim3(8, 25), blk, 0, stream>>>(
        bufX, wP[3], bufY, st + stOff[3], 128, 19, 19, 10, 2, 1, 1152, 256, 36, 1600, 100);
    ab_kernel<<<1, blk, 0, stream>>>(st + stOff[3], g[3], bt[3], ab + abOff[3], 256, 1.0 / 1600);
    prep_kernel<<<dim3(1, 16 * 256), blk, 0, stream>>>(bufY, ab + abOff[3], bufX, 256, 100);

    // ---- L5: 1x1, 256->128, 10x10, P=1600, PI=100, K=256, OB=8
    adder_conv<8, false><<<dim3(4, 25), blk, 0, stream>>>(
        bufX, wP[4], bufY, st + stOff[4], 256, 10, 10, 10, 1, 0, 256, 128, 8, 1600, 100);
    ab_kernel<<<1, blk, 0, stream>>>(st + stOff[4], g[4], bt[4], ab + abOff[4], 128, 1.0 / 1600);
    prep_kernel<<<dim3(1, 16 * 128), blk, 0, stream>>>(bufY, ab + abOff[4], bufX, 128, 100);

    // ---- L6: 3x3 s2 p0, 128->256, 10->4, P=256, PI=16, K=1152, OB=4
    adder_conv<4, true><<<dim3(16, 4), blk, 0, stream>>>(
        bufX, wP[5], bufY, st + stOff[5], 128, 10, 10, 4, 2, 0, 1152, 256, 36, 256, 16);
    ab_kernel<<<1, blk, 0, stream>>>(st + stOff[5], g[5], bt[5], ab + abOff[5], 256, 1.0 / 256);
    prep_kernel<<<dim3(1, 16 * 256), blk, 0, stream>>>(bufY, ab + abOff[5], (float*)d_out, 256, 16);
}